// Round 8
// baseline (154.349 us; speedup 1.0000x reference)
//
#include <hip/hip_runtime.h>
#include <hip/hip_bf16.h>

// Problem constants (match reference)
#define N_OUT_ROWS 250000
#define TILES 15625      // 16-row output tiles
#define NBLK 512         // 2 blocks/CU (66.5KB LDS each) -- all co-resident
#define WPB 4            // waves per block
#define NWAVES (NBLK * WPB)  // 2048
#define BN_EPS 1e-5f

typedef __attribute__((ext_vector_type(8))) short bf16x8;
typedef __attribute__((ext_vector_type(8))) unsigned short u16x8;
typedef __attribute__((ext_vector_type(4))) float f32x4;

static __device__ __forceinline__ unsigned short f2bf(float f) {
  union { float f; unsigned u; } v; v.f = f;
  unsigned r = v.u + 0x7FFFu + ((v.u >> 16) & 1u);
  return (unsigned short)(r >> 16);
}
static __device__ __forceinline__ float bf2f(unsigned short s) {
  union { unsigned u; float f; } v; v.u = ((unsigned)s) << 16;
  return v.f;
}

// Fire-and-forget 16B gather into LDS (per-lane global src, linear LDS dest).
#define GLOAD_LDS16(gsrc, ldst)                                                \
  __builtin_amdgcn_global_load_lds(                                            \
      (const __attribute__((address_space(1))) unsigned int*)(gsrc),           \
      (__attribute__((address_space(3))) unsigned int*)(ldst), 16, 0, 0)

// Per-wave contiguous tile range split of TILES over NWAVES waves.
static __device__ __forceinline__ int tile_start(int g) {
  const int q = TILES / NWAVES;    // 7
  const int rem = TILES % NWAVES;  // 1289
  return (g < rem) ? g * (q + 1) : rem * (q + 1) + (g - rem) * q;
}

// Prep: weights f32 -> bf16 fragment layout in d_ws.
__global__ void k_prep(const float* __restrict__ w,
                       unsigned short* __restrict__ bfrag) {
  const int i = blockIdx.x * 256 + threadIdx.x;  // 0..2047
  const int f = i >> 6, l = i & 63;
  const int kt = f >> 2, ct = f & 3, rr = l & 15, gg = l >> 4;
  u16x8 o;
  #pragma unroll
  for (int j = 0; j < 8; ++j)
    o[j] = f2bf(w[(kt * 32 + gg * 8 + j) * 64 + ct * 16 + rr]);
  *reinterpret_cast<u16x8*>(bfrag + i * 8) = o;
}

// Fused gather + bf16-MFMA GEMM + BN stats + grid barrier + BN normalize.
// Phase 1 is the r3/r7-proven structure (direct idx loads -> back-to-back
// global_load_lds burst; vmcnt(0)/tile count-independent drain; block-level
// stats, 128 atomics/block; bf16 intermediate halves write bytes). Grid
// barrier: 512 blocks all co-resident (2/CU by launch_bounds+LDS), arrival
// atomic + sleep-spin; stats cross XCDs via device-scope atomics + release/
// acquire. Phase 2: each block normalizes ITS OWN tile range -- the bf16
// lines it just wrote are in its own XCD's L2 (no cross-XCD read needed).
__global__ __launch_bounds__(256, 2)
void k_fused(const float* __restrict__ x, const int* __restrict__ neigh,
             const unsigned short* __restrict__ bfrag,
             unsigned short* __restrict__ obf, float* __restrict__ out,
             float* __restrict__ stats, unsigned int* __restrict__ bar,
             const float* __restrict__ gamma, const float* __restrict__ beta) {
  __shared__ __align__(16) unsigned char Abuf_all[WPB][16384];  // 64 KB
  __shared__ float wpart[WPB][128];
  __shared__ float sc[64], bs[64];

  const int tid = threadIdx.x;
  const int lane = tid & 63;
  const int widx = tid >> 6;
  unsigned char* Abuf = Abuf_all[widx];

  // B fragments fully in registers (32 frags = 128 VGPR).
  bf16x8 bf[8][4];
  #pragma unroll
  for (int kt = 0; kt < 8; ++kt)
    #pragma unroll
    for (int ct = 0; ct < 4; ++ct)
      bf[kt][ct] = *reinterpret_cast<const bf16x8*>(
          bfrag + ((kt * 4 + ct) * 64 + lane) * 8);

  const int gw = blockIdx.x * WPB + widx;  // 0..2047
  const int start = tile_start(gw);
  const int cnt = tile_start(gw + 1) - start;

  const int r = lane & 15;     // A row within tile / C col-within-group
  const int g4 = lane >> 4;    // k-slice group
  const int seg = lane & 7;    // 16B segment within a 128B x-row
  const int ktl = lane >> 3;   // which neighbor this lane fetches
  const int swz = (r & 7) << 4;
  const int rdbase = (r << 10) + (g4 << 5);

  float sacc[4] = {0.f, 0.f, 0.f, 0.f};
  float qacc[4] = {0.f, 0.f, 0.f, 0.f};

  for (int k = 0; k < cnt; ++k) {
    const int t = start + k;
    const int n0 = t << 4;

    // Direct idx loads: addresses in VGPRs before the gather burst.
    int idxv[16];
    #pragma unroll
    for (int m = 0; m < 16; ++m)
      idxv[m] = neigh[(n0 + m) * 8 + ktl];

    // WAR guard: previous tile's ds_reads fully retired before overwriting.
    asm volatile("s_waitcnt lgkmcnt(0)" ::: "memory");
    __builtin_amdgcn_sched_barrier(0);

    // 16 gathers back-to-back; source segment pre-permuted (seg^(j&7)) =
    // XOR-swizzled linear LDS layout (Rule 21).
    #pragma unroll
    for (int j = 0; j < 16; ++j) {
      const float* src = x + (size_t)idxv[j] * 32 + ((seg ^ (j & 7)) << 2);
      GLOAD_LDS16(src, Abuf + j * 1024);
    }

    // Count-independent drain (immune to scheduler reordering).
    asm volatile("s_waitcnt vmcnt(0)" ::: "memory");
    __builtin_amdgcn_sched_barrier(0);

    f32x4 acc[4];
    #pragma unroll
    for (int ct = 0; ct < 4; ++ct) acc[ct] = (f32x4){0.f, 0.f, 0.f, 0.f};

    #pragma unroll
    for (int kt = 0; kt < 8; ++kt) {
      const int o0 = rdbase + (kt << 7);
      const f32x4 a0 = *reinterpret_cast<const f32x4*>(Abuf + (o0 ^ swz));
      const f32x4 a1 = *reinterpret_cast<const f32x4*>(Abuf + ((o0 + 16) ^ swz));
      union { bf16x8 v; __hip_bfloat162 h[4]; } af;
      af.h[0] = __float22bfloat162_rn(make_float2(a0[0], a0[1]));
      af.h[1] = __float22bfloat162_rn(make_float2(a0[2], a0[3]));
      af.h[2] = __float22bfloat162_rn(make_float2(a1[0], a1[1]));
      af.h[3] = __float22bfloat162_rn(make_float2(a1[2], a1[3]));
      #pragma unroll
      for (int ct = 0; ct < 4; ++ct)
        acc[ct] = __builtin_amdgcn_mfma_f32_16x16x32_bf16(af.v, bf[kt][ct],
                                                          acc[ct], 0, 0, 0);
    }

    // bf16 intermediate write: col = ct*16 + r, row = g4*4 + j.
    const int rbase = n0 + g4 * 4;
    #pragma unroll
    for (int ct = 0; ct < 4; ++ct) {
      #pragma unroll
      for (int j = 0; j < 4; ++j)
        obf[(rbase + j) * 64 + ct * 16 + r] = f2bf(acc[ct][j]);
      sacc[ct] += acc[ct][0] + acc[ct][1] + acc[ct][2] + acc[ct][3];
      qacc[ct] += acc[ct][0] * acc[ct][0] + acc[ct][1] * acc[ct][1] +
                  acc[ct][2] * acc[ct][2] + acc[ct][3] * acc[ct][3];
    }
  }

  // Block-level BN stats reduction: 128 device-scope atomics per block.
  #pragma unroll
  for (int ct = 0; ct < 4; ++ct) {
    sacc[ct] += __shfl_xor(sacc[ct], 16);
    qacc[ct] += __shfl_xor(qacc[ct], 16);
    sacc[ct] += __shfl_xor(sacc[ct], 32);
    qacc[ct] += __shfl_xor(qacc[ct], 32);
  }
  if (lane < 16) {
    #pragma unroll
    for (int ct = 0; ct < 4; ++ct) {
      wpart[widx][ct * 16 + lane] = sacc[ct];
      wpart[widx][64 + ct * 16 + lane] = qacc[ct];
    }
  }
  __syncthreads();
  if (tid < 128) {
    atomicAdd(&stats[tid], wpart[0][tid] + wpart[1][tid] +
                           wpart[2][tid] + wpart[3][tid]);
  }

  // ---- grid barrier (all 512 blocks co-resident by construction) ----
  __syncthreads();  // all waves' stats atomics issued & drained (vmcnt in barrier)
  if (tid == 0) {
    __threadfence();  // release: obf stores + stats atomics ordered before arrive
    __hip_atomic_fetch_add(bar, 1u, __ATOMIC_ACQ_REL, __HIP_MEMORY_SCOPE_AGENT);
    unsigned v;
    do {
      v = __hip_atomic_load(bar, __ATOMIC_ACQUIRE, __HIP_MEMORY_SCOPE_AGENT);
      if (v < NBLK) __builtin_amdgcn_s_sleep(32);
    } while (v < NBLK);
  }
  __syncthreads();

  // ---- phase 2: BN finalize over this block's own tile range (L2-hot) ----
  if (tid < 64) {
    const float inv = 1.0f / (float)N_OUT_ROWS;
    const float sum = __hip_atomic_load(&stats[tid], __ATOMIC_RELAXED,
                                        __HIP_MEMORY_SCOPE_AGENT);
    const float ssq = __hip_atomic_load(&stats[64 + tid], __ATOMIC_RELAXED,
                                        __HIP_MEMORY_SCOPE_AGENT);
    const float mean = sum * inv;
    const float var = ssq * inv - mean * mean;
    const float scale = rsqrtf(var + BN_EPS) * gamma[tid];
    sc[tid] = scale;
    bs[tid] = beta[tid] - mean * scale;
  }
  __syncthreads();

  const int bt0 = tile_start(blockIdx.x * WPB);
  const int bt1 = tile_start(blockIdx.x * WPB + WPB);
  const int nchunk = (bt1 - bt0) * 128;  // 128 u16x8-chunks per tile
  const int base = bt0 * 128;
  for (int i = tid; i < nchunk; i += 256) {
    const int c = base + i;
    const u16x8 v = *reinterpret_cast<const u16x8*>(obf + (size_t)c * 8);
    const int d0 = (c & 7) << 3;  // 8 chunks per 64-ch row
    float4 o0, o1;
    o0.x = bf2f(v[0]) * sc[d0 + 0] + bs[d0 + 0];
    o0.y = bf2f(v[1]) * sc[d0 + 1] + bs[d0 + 1];
    o0.z = bf2f(v[2]) * sc[d0 + 2] + bs[d0 + 2];
    o0.w = bf2f(v[3]) * sc[d0 + 3] + bs[d0 + 3];
    o1.x = bf2f(v[4]) * sc[d0 + 4] + bs[d0 + 4];
    o1.y = bf2f(v[5]) * sc[d0 + 5] + bs[d0 + 5];
    o1.z = bf2f(v[6]) * sc[d0 + 6] + bs[d0 + 6];
    o1.w = bf2f(v[7]) * sc[d0 + 7] + bs[d0 + 7];
    reinterpret_cast<float4*>(out)[c * 2] = o0;
    reinterpret_cast<float4*>(out)[c * 2 + 1] = o1;
  }
}

// ---------- fallback (ws too small): r3-style f32 two-kernel path ----------
__global__ __launch_bounds__(256, 2)
void k_gemm_f32(const float* __restrict__ x, const int* __restrict__ neigh,
                const unsigned short* __restrict__ bfrag,
                float* __restrict__ outf, float* __restrict__ stats) {
  __shared__ __align__(16) unsigned char Abuf_all[WPB][16384];
  __shared__ float wpart[WPB][128];
  const int tid = threadIdx.x;
  const int lane = tid & 63;
  const int widx = tid >> 6;
  unsigned char* Abuf = Abuf_all[widx];
  bf16x8 bf[8][4];
  #pragma unroll
  for (int kt = 0; kt < 8; ++kt)
    #pragma unroll
    for (int ct = 0; ct < 4; ++ct)
      bf[kt][ct] = *reinterpret_cast<const bf16x8*>(
          bfrag + ((kt * 4 + ct) * 64 + lane) * 8);
  const int gw = blockIdx.x * WPB + widx;
  const int start = tile_start(gw), cnt = tile_start(gw + 1) - start;
  const int r = lane & 15, g4 = lane >> 4, seg = lane & 7, ktl = lane >> 3;
  const int swz = (r & 7) << 4, rdbase = (r << 10) + (g4 << 5);
  float sacc[4] = {0,0,0,0}, qacc[4] = {0,0,0,0};
  for (int k = 0; k < cnt; ++k) {
    const int n0 = (start + k) << 4;
    int idxv[16];
    #pragma unroll
    for (int m = 0; m < 16; ++m) idxv[m] = neigh[(n0 + m) * 8 + ktl];
    asm volatile("s_waitcnt lgkmcnt(0)" ::: "memory");
    __builtin_amdgcn_sched_barrier(0);
    #pragma unroll
    for (int j = 0; j < 16; ++j) {
      const float* src = x + (size_t)idxv[j] * 32 + ((seg ^ (j & 7)) << 2);
      GLOAD_LDS16(src, Abuf + j * 1024);
    }
    asm volatile("s_waitcnt vmcnt(0)" ::: "memory");
    __builtin_amdgcn_sched_barrier(0);
    f32x4 acc[4];
    #pragma unroll
    for (int ct = 0; ct < 4; ++ct) acc[ct] = (f32x4){0,0,0,0};
    #pragma unroll
    for (int kt = 0; kt < 8; ++kt) {
      const int o0 = rdbase + (kt << 7);
      const f32x4 a0 = *reinterpret_cast<const f32x4*>(Abuf + (o0 ^ swz));
      const f32x4 a1 = *reinterpret_cast<const f32x4*>(Abuf + ((o0 + 16) ^ swz));
      union { bf16x8 v; __hip_bfloat162 h[4]; } af;
      af.h[0] = __float22bfloat162_rn(make_float2(a0[0], a0[1]));
      af.h[1] = __float22bfloat162_rn(make_float2(a0[2], a0[3]));
      af.h[2] = __float22bfloat162_rn(make_float2(a1[0], a1[1]));
      af.h[3] = __float22bfloat162_rn(make_float2(a1[2], a1[3]));
      #pragma unroll
      for (int ct = 0; ct < 4; ++ct)
        acc[ct] = __builtin_amdgcn_mfma_f32_16x16x32_bf16(af.v, bf[kt][ct],
                                                          acc[ct], 0, 0, 0);
    }
    const int rbase = n0 + g4 * 4;
    #pragma unroll
    for (int ct = 0; ct < 4; ++ct) {
      #pragma unroll
      for (int j = 0; j < 4; ++j)
        outf[(rbase + j) * 64 + ct * 16 + r] = acc[ct][j];
      sacc[ct] += acc[ct][0] + acc[ct][1] + acc[ct][2] + acc[ct][3];
      qacc[ct] += acc[ct][0] * acc[ct][0] + acc[ct][1] * acc[ct][1] +
                  acc[ct][2] * acc[ct][2] + acc[ct][3] * acc[ct][3];
    }
  }
  #pragma unroll
  for (int ct = 0; ct < 4; ++ct) {
    sacc[ct] += __shfl_xor(sacc[ct], 16);
    qacc[ct] += __shfl_xor(qacc[ct], 16);
    sacc[ct] += __shfl_xor(sacc[ct], 32);
    qacc[ct] += __shfl_xor(qacc[ct], 32);
  }
  if (lane < 16) {
    #pragma unroll
    for (int ct = 0; ct < 4; ++ct) {
      wpart[widx][ct * 16 + lane] = sacc[ct];
      wpart[widx][64 + ct * 16 + lane] = qacc[ct];
    }
  }
  __syncthreads();
  if (tid < 128)
    atomicAdd(&stats[tid], wpart[0][tid] + wpart[1][tid] +
                           wpart[2][tid] + wpart[3][tid]);
}

__global__ __launch_bounds__(256)
void k_bn_f32(float* __restrict__ out, const float* __restrict__ stats,
              const float* __restrict__ gamma, const float* __restrict__ beta) {
  __shared__ float sc[64], bs[64];
  if (threadIdx.x < 64) {
    const int d = threadIdx.x;
    const float inv = 1.0f / (float)N_OUT_ROWS;
    const float mean = stats[d] * inv;
    const float var = stats[64 + d] * inv - mean * mean;
    const float scale = rsqrtf(var + BN_EPS) * gamma[d];
    sc[d] = scale;
    bs[d] = beta[d] - mean * scale;
  }
  __syncthreads();
  const int total4 = N_OUT_ROWS * 64 / 4;
  float4* o4 = reinterpret_cast<float4*>(out);
  for (int i = blockIdx.x * blockDim.x + threadIdx.x; i < total4;
       i += gridDim.x * blockDim.x) {
    const int d0 = (i & 15) << 2;
    float4 v = o4[i];
    v.x = v.x * sc[d0]     + bs[d0];
    v.y = v.y * sc[d0 + 1] + bs[d0 + 1];
    v.z = v.z * sc[d0 + 2] + bs[d0 + 2];
    v.w = v.w * sc[d0 + 3] + bs[d0 + 3];
    o4[i] = v;
  }
}

extern "C" void kernel_launch(void* const* d_in, const int* in_sizes, int n_in,
                              void* d_out, int out_size, void* d_ws, size_t ws_size,
                              hipStream_t stream) {
  const float* x     = (const float*)d_in[0];
  const int*   neigh = (const int*)d_in[1];
  const float* w     = (const float*)d_in[2];
  const float* gamma = (const float*)d_in[3];
  const float* beta  = (const float*)d_in[4];
  float* out = (float*)d_out;

  float* stats = (float*)d_ws;                                    // 512 B
  unsigned int* bar = (unsigned int*)((char*)d_ws + 512);         // 4 B
  unsigned short* bfrag = (unsigned short*)((char*)d_ws + 1024);  // 32 KB
  unsigned short* obf = (unsigned short*)((char*)d_ws + 65536);   // 32 MB

  const bool fused =
      ws_size >= (size_t)65536 + (size_t)N_OUT_ROWS * 64 * 2;

  hipMemsetAsync(d_ws, 0, 1024, stream);  // stats + barrier counter
  k_prep<<<8, 256, 0, stream>>>(w, bfrag);
  if (fused) {
    k_fused<<<NBLK, 256, 0, stream>>>(x, neigh, bfrag, obf, out, stats, bar,
                                      gamma, beta);
  } else {
    k_gemm_f32<<<NBLK, 256, 0, stream>>>(x, neigh, bfrag, out, stats);
    k_bn_f32<<<2048, 256, 0, stream>>>(out, stats, gamma, beta);
  }
}

// Round 9
// 84.368 us; speedup vs baseline: 1.8295x; 1.8295x over previous
//
#include <hip/hip_runtime.h>
#include <hip/hip_bf16.h>

// Problem constants (match reference)
#define N_OUT_ROWS 250000
#define TILES 15625      // 16-row output tiles
#define NBLK 768         // 3 blocks/CU (launch_bounds(256,3); LDS 34.8KB)
#define WPB 4            // waves per block = 2 wave-pairs
#define BN_EPS 1e-5f

#define SB() __builtin_amdgcn_sched_barrier(0)

typedef __attribute__((ext_vector_type(8))) short bf16x8;
typedef __attribute__((ext_vector_type(8))) unsigned short u16x8;
typedef __attribute__((ext_vector_type(4))) float f32x4;

static __device__ __forceinline__ unsigned short f2bf(float f) {
  union { float f; unsigned u; } v; v.f = f;
  unsigned r = v.u + 0x7FFFu + ((v.u >> 16) & 1u);
  return (unsigned short)(r >> 16);
}
static __device__ __forceinline__ float bf2f(unsigned short s) {
  union { unsigned u; float f; } v; v.u = ((unsigned)s) << 16;
  return v.f;
}

// Fire-and-forget 16B gather into LDS (per-lane global src, linear LDS dest).
#define GLOAD_LDS16(gsrc, ldst)                                                \
  __builtin_amdgcn_global_load_lds(                                            \
      (const __attribute__((address_space(1))) unsigned int*)(gsrc),           \
      (__attribute__((address_space(3))) unsigned int*)(ldst), 16, 0, 0)

// Prep: weights f32 -> bf16 fragment layout in d_ws, zero stats.
__global__ void k_prep(const float* __restrict__ w,
                       unsigned short* __restrict__ bfrag,
                       float* __restrict__ stats) {
  const int i = blockIdx.x * 256 + threadIdx.x;  // 0..2047
  if (i < 128) stats[i] = 0.f;
  const int f = i >> 6, l = i & 63;
  const int kt = f >> 2, ct = f & 3, rr = l & 15, gg = l >> 4;
  u16x8 o;
  #pragma unroll
  for (int j = 0; j < 8; ++j)
    o[j] = f2bf(w[(kt * 32 + gg * 8 + j) * 64 + ct * 16 + rr]);
  *reinterpret_cast<u16x8*>(bfrag + i * 8) = o;
}

// Fused gather + bf16-MFMA GEMM + BN partials, WAVE-PAIR ct-split.
// Why: r8 profile showed VGPR_Count=120 + AGPR-parked B-frags (~250 total
// regs/wave) -> register file pins occupancy at 2 waves/SIMD; r3-vs-r5 showed
// perf scales with wave concurrency (queue-depth-bound gather). Splitting the
// 4 output ct-groups across a wave PAIR halves per-wave B to 64 VGPRs ->
// launch_bounds(256,3) holds without spills -> 3 blocks/CU, 12 waves/CU
// (+50% outstanding gathers). The pair shares one 16KB Abuf: each wave
// gathers 8 of the 16 rows (back-to-back burst preserved, r6 lesson), both
// read all 16 rows. Sync is a plain 2-barrier loop with own-wave vmcnt(0)
// before the barrier (count-independent, r4-race-immune). Pairs in a block
// interleave tiles stride-2 with uniform trip count (inactive tail guarded,
// barriers unconditional).
template <bool BF16OUT>
__global__ __launch_bounds__(256, 3)
void k_gemm(const float* __restrict__ x, const int* __restrict__ neigh,
            const unsigned short* __restrict__ bfrag,
            float* __restrict__ outf, unsigned short* __restrict__ outb,
            float* __restrict__ stats) {
  __shared__ __align__(16) unsigned char Abuf_all[2][16384];  // one per pair
  __shared__ float wpart[WPB][128];

  const int tid = threadIdx.x;
  const int lane = tid & 63;
  const int widx = tid >> 6;
  const int pairid = widx >> 1;   // which pair (0,1)
  const int half = widx & 1;      // 0: gathers rows 0-7, ct 0-1; 1: rows 8-15, ct 2-3
  const int ctg0 = half << 1;     // this wave's first global ct
  unsigned char* Abuf = Abuf_all[pairid];

  // B fragments for this wave's 2 ct-groups only: 16 frags = 64 VGPR.
  bf16x8 bf[8][2];
  #pragma unroll
  for (int kt = 0; kt < 8; ++kt)
    #pragma unroll
    for (int c = 0; c < 2; ++c)
      bf[kt][c] = *reinterpret_cast<const bf16x8*>(
          bfrag + ((kt * 4 + ctg0 + c) * 64 + lane) * 8);

  // Contiguous tile range per BLOCK; pairs interleave stride-2 within it so
  // both pairs execute the same number of barrier iterations.
  const int b = blockIdx.x;
  const int q = TILES / NBLK;      // 20
  const int rem = TILES % NBLK;    // 265
  const int s_b = (b < rem) ? b * (q + 1) : rem * (q + 1) + (b - rem) * q;
  const int c_b = q + (b < rem ? 1 : 0);
  const int e_b = s_b + c_b;
  const int K = (c_b + 1) >> 1;

  const int r = lane & 15;     // A row within tile / C col-within-group
  const int g4 = lane >> 4;    // k-slice group
  const int seg = lane & 7;    // 16B segment within a 128B x-row
  const int ktl = lane >> 3;   // which neighbor this lane fetches
  const int swz = (r & 7) << 4;
  const int rdbase = (r << 10) + (g4 << 5);
  const int jbase = half << 3; // this wave's 8-row gather slice

  float sacc[2] = {0.f, 0.f};
  float qacc[2] = {0.f, 0.f};

  for (int k2 = 0; k2 < K; ++k2) {
    const int t = s_b + (k2 << 1) + pairid;
    const bool active = t < e_b;

    // Direct idx loads (addresses in VGPRs before the burst; r6 lesson).
    int idxv[8];
    if (active) {
      #pragma unroll
      for (int m = 0; m < 8; ++m)
        idxv[m] = neigh[((t << 4) + jbase + m) * 8 + ktl];
    }

    __syncthreads();  // WAR: whole pair done reading the shared buffer

    if (active) {
      SB();
      // 8 gathers back-to-back: instr j stages row (jbase+j)'s 8 neighbors.
      // Source segment pre-permuted (seg^(ch&7)) = XOR-swizzled linear LDS
      // layout (Rule 21); read side applies the same involution.
      #pragma unroll
      for (int j = 0; j < 8; ++j) {
        const int ch = jbase + j;
        const float* src = x + (size_t)idxv[j] * 32 + ((seg ^ (ch & 7)) << 2);
        GLOAD_LDS16(src, Abuf + ch * 1024);
      }
      SB();
      // Own-wave drain (count-independent). Partner's data visibility is
      // established by the barrier below (partner drained its own too).
      asm volatile("s_waitcnt vmcnt(0)" ::: "memory");
    }
    __syncthreads();  // all 16 rows landed for this pair's tile

    if (active) {
      f32x4 acc[2];
      acc[0] = (f32x4){0.f, 0.f, 0.f, 0.f};
      acc[1] = (f32x4){0.f, 0.f, 0.f, 0.f};

      #pragma unroll
      for (int kt = 0; kt < 8; ++kt) {
        const int o0 = rdbase + (kt << 7);
        const f32x4 a0 = *reinterpret_cast<const f32x4*>(Abuf + (o0 ^ swz));
        const f32x4 a1 = *reinterpret_cast<const f32x4*>(Abuf + ((o0 + 16) ^ swz));
        union { bf16x8 v; __hip_bfloat162 h[4]; } af;
        af.h[0] = __float22bfloat162_rn(make_float2(a0[0], a0[1]));
        af.h[1] = __float22bfloat162_rn(make_float2(a0[2], a0[3]));
        af.h[2] = __float22bfloat162_rn(make_float2(a1[0], a1[1]));
        af.h[3] = __float22bfloat162_rn(make_float2(a1[2], a1[3]));
        acc[0] = __builtin_amdgcn_mfma_f32_16x16x32_bf16(af.v, bf[kt][0],
                                                         acc[0], 0, 0, 0);
        acc[1] = __builtin_amdgcn_mfma_f32_16x16x32_bf16(af.v, bf[kt][1],
                                                         acc[1], 0, 0, 0);
      }

      // C write: col = (ctg0+c)*16 + r, row = g4*4 + j (m89-verified layout).
      const int rbase = (t << 4) + g4 * 4;
      #pragma unroll
      for (int c = 0; c < 2; ++c) {
        #pragma unroll
        for (int j = 0; j < 4; ++j) {
          const int off = (rbase + j) * 64 + (ctg0 + c) * 16 + r;
          if (BF16OUT) outb[off] = f2bf(acc[c][j]);
          else         outf[off] = acc[c][j];
        }
        sacc[c] += acc[c][0] + acc[c][1] + acc[c][2] + acc[c][3];
        qacc[c] += acc[c][0] * acc[c][0] + acc[c][1] * acc[c][1] +
                   acc[c][2] * acc[c][2] + acc[c][3] * acc[c][3];
      }
    }
  }

  // Block-level BN stats reduction: shuffle across g4 groups, LDS combine
  // (each wave owns 2 ct slots, zeroes the other 2), 128 atomics per block.
  #pragma unroll
  for (int c = 0; c < 2; ++c) {
    sacc[c] += __shfl_xor(sacc[c], 16);
    qacc[c] += __shfl_xor(qacc[c], 16);
    sacc[c] += __shfl_xor(sacc[c], 32);
    qacc[c] += __shfl_xor(qacc[c], 32);
  }
  if (lane < 16) {
    const int other = ctg0 ^ 2;
    #pragma unroll
    for (int c = 0; c < 2; ++c) {
      wpart[widx][(ctg0 + c) * 16 + lane] = sacc[c];
      wpart[widx][64 + (ctg0 + c) * 16 + lane] = qacc[c];
      wpart[widx][(other + c) * 16 + lane] = 0.f;
      wpart[widx][64 + (other + c) * 16 + lane] = 0.f;
    }
  }
  __syncthreads();
  if (tid < 128) {
    atomicAdd(&stats[tid], wpart[0][tid] + wpart[1][tid] +
                           wpart[2][tid] + wpart[3][tid]);
  }
}

// Finalize BN: y = (v - mean) * rsqrt(var+eps) * gamma + beta.
// BF16IN: read bf16 intermediate (L3-hot), write f32 output.
template <bool BF16IN>
__global__ __launch_bounds__(256)
void k_bn(float* __restrict__ out, const unsigned short* __restrict__ inb,
          const float* __restrict__ stats, const float* __restrict__ gamma,
          const float* __restrict__ beta) {
  __shared__ float sc[64], bs[64];
  if (threadIdx.x < 64) {
    const int d = threadIdx.x;
    const float inv = 1.0f / (float)N_OUT_ROWS;
    const float mean = stats[d] * inv;
    const float var = stats[64 + d] * inv - mean * mean;
    const float rstd = rsqrtf(var + BN_EPS);
    const float scale = rstd * gamma[d];
    sc[d] = scale;
    bs[d] = beta[d] - mean * scale;
  }
  __syncthreads();

  if (BF16IN) {
    const int total8 = N_OUT_ROWS * 64 / 8;  // 2M chunks of 8 elems
    for (int i = blockIdx.x * blockDim.x + threadIdx.x; i < total8;
         i += gridDim.x * blockDim.x) {
      const int d0 = (i & 7) << 3;  // 8 chunks per 64-ch row
      const u16x8 v = *reinterpret_cast<const u16x8*>(inb + i * 8);
      float4 o0, o1;
      o0.x = bf2f(v[0]) * sc[d0 + 0] + bs[d0 + 0];
      o0.y = bf2f(v[1]) * sc[d0 + 1] + bs[d0 + 1];
      o0.z = bf2f(v[2]) * sc[d0 + 2] + bs[d0 + 2];
      o0.w = bf2f(v[3]) * sc[d0 + 3] + bs[d0 + 3];
      o1.x = bf2f(v[4]) * sc[d0 + 4] + bs[d0 + 4];
      o1.y = bf2f(v[5]) * sc[d0 + 5] + bs[d0 + 5];
      o1.z = bf2f(v[6]) * sc[d0 + 6] + bs[d0 + 6];
      o1.w = bf2f(v[7]) * sc[d0 + 7] + bs[d0 + 7];
      reinterpret_cast<float4*>(out)[i * 2] = o0;
      reinterpret_cast<float4*>(out)[i * 2 + 1] = o1;
    }
  } else {
    const int total4 = N_OUT_ROWS * 64 / 4;
    float4* o4 = reinterpret_cast<float4*>(out);
    for (int i = blockIdx.x * blockDim.x + threadIdx.x; i < total4;
         i += gridDim.x * blockDim.x) {
      const int d0 = (i & 15) << 2;
      float4 v = o4[i];
      v.x = v.x * sc[d0]     + bs[d0];
      v.y = v.y * sc[d0 + 1] + bs[d0 + 1];
      v.z = v.z * sc[d0 + 2] + bs[d0 + 2];
      v.w = v.w * sc[d0 + 3] + bs[d0 + 3];
      o4[i] = v;
    }
  }
}

extern "C" void kernel_launch(void* const* d_in, const int* in_sizes, int n_in,
                              void* d_out, int out_size, void* d_ws, size_t ws_size,
                              hipStream_t stream) {
  const float* x     = (const float*)d_in[0];
  const int*   neigh = (const int*)d_in[1];
  const float* w     = (const float*)d_in[2];
  const float* gamma = (const float*)d_in[3];
  const float* beta  = (const float*)d_in[4];
  float* out = (float*)d_out;

  float* stats = (float*)d_ws;                                    // 512 B
  unsigned short* bfrag = (unsigned short*)((char*)d_ws + 1024);  // 32 KB
  unsigned short* obf = (unsigned short*)((char*)d_ws + 65536);   // 32 MB

  const bool bf16path =
      ws_size >= (size_t)65536 + (size_t)N_OUT_ROWS * 64 * 2;

  k_prep<<<8, 256, 0, stream>>>(w, bfrag, stats);
  if (bf16path) {
    k_gemm<true><<<NBLK, 256, 0, stream>>>(x, neigh, bfrag, nullptr, obf, stats);
    k_bn<true><<<2048, 256, 0, stream>>>(out, obf, stats, gamma, beta);
  } else {
    k_gemm<false><<<NBLK, 256, 0, stream>>>(x, neigh, bfrag, out, nullptr, stats);
    k_bn<false><<<2048, 256, 0, stream>>>(out, nullptr, stats, gamma, beta);
  }
}

// Round 10
// 80.352 us; speedup vs baseline: 1.9209x; 1.0500x over previous
//
#include <hip/hip_runtime.h>
#include <hip/hip_bf16.h>

// Problem constants (match reference)
#define N_OUT_ROWS 250000
#define TILES 15625      // 16-row output tiles
#define NBLK 512         // 2 blocks/CU (66KB LDS each)
#define WPB 4            // waves per block
#define NWAVES (NBLK * WPB)  // 2048
#define BN_EPS 1e-5f

typedef __attribute__((ext_vector_type(8))) short bf16x8;
typedef __attribute__((ext_vector_type(8))) unsigned short u16x8;
typedef __attribute__((ext_vector_type(4))) float f32x4;

static __device__ __forceinline__ unsigned short f2bf(float f) {
  union { float f; unsigned u; } v; v.f = f;
  unsigned r = v.u + 0x7FFFu + ((v.u >> 16) & 1u);
  return (unsigned short)(r >> 16);
}
static __device__ __forceinline__ float bf2f(unsigned short s) {
  union { unsigned u; float f; } v; v.u = ((unsigned)s) << 16;
  return v.f;
}

// Fire-and-forget 16B gather into LDS (per-lane global src, linear LDS dest).
#define GLOAD_LDS16(gsrc, ldst)                                                \
  __builtin_amdgcn_global_load_lds(                                            \
      (const __attribute__((address_space(1))) unsigned int*)(gsrc),           \
      (__attribute__((address_space(3))) unsigned int*)(ldst), 16, 0, 0)

// Prep: weights f32 -> bf16 fragment layout in d_ws, zero stats.
__global__ void k_prep(const float* __restrict__ w,
                       unsigned short* __restrict__ bfrag,
                       float* __restrict__ stats) {
  const int i = blockIdx.x * 256 + threadIdx.x;  // 0..2047
  if (i < 128) stats[i] = 0.f;
  const int f = i >> 6, l = i & 63;
  const int kt = f >> 2, ct = f & 3, rr = l & 15, gg = l >> 4;
  u16x8 o;
  #pragma unroll
  for (int j = 0; j < 8; ++j)
    o[j] = f2bf(w[(kt * 32 + gg * 8 + j) * 64 + ct * 16 + rr]);
  *reinterpret_cast<u16x8*>(bfrag + i * 8) = o;
}

// Fused gather + bf16-MFMA GEMM + BN partials. Measured-best structure
// (r7 = 80.4us): direct per-lane idx loads so all 16 gather addresses are in
// VGPRs and the global_load_lds burst issues BACK-TO-BACK (max queue depth;
// r5/r6/r9 A/B: anything that smears or shortens the burst, adds inter-wave
// coupling, or trades queue depth for occupancy regresses); vmcnt(0) per tile
// (count-independent, race-immune per r4); block-level stats (LDS + barrier,
// 128 atomics/block); bf16 intermediate (halves write bytes, r7's +5us win).
template <bool BF16OUT>
__global__ __launch_bounds__(256, 2)
void k_gemm(const float* __restrict__ x, const int* __restrict__ neigh,
            const unsigned short* __restrict__ bfrag,
            float* __restrict__ outf, unsigned short* __restrict__ outb,
            float* __restrict__ stats) {
  __shared__ __align__(16) unsigned char Abuf_all[WPB][16384];  // 64 KB
  __shared__ float wpart[WPB][128];

  const int tid = threadIdx.x;
  const int lane = tid & 63;
  const int widx = tid >> 6;
  unsigned char* Abuf = Abuf_all[widx];

  // B fragments fully in registers (32 frags = 128 VGPR).
  bf16x8 bf[8][4];
  #pragma unroll
  for (int kt = 0; kt < 8; ++kt)
    #pragma unroll
    for (int ct = 0; ct < 4; ++ct)
      bf[kt][ct] = *reinterpret_cast<const bf16x8*>(
          bfrag + ((kt * 4 + ct) * 64 + lane) * 8);

  // Contiguous tile range per wave (sequential neigh reads).
  const int gw = blockIdx.x * WPB + widx;  // 0..2047
  const int q = TILES / NWAVES;            // 7
  const int rem = TILES % NWAVES;          // 1289
  const int start = (gw < rem) ? gw * (q + 1) : rem * (q + 1) + (gw - rem) * q;
  const int cnt = q + (gw < rem ? 1 : 0);

  const int r = lane & 15;     // A row within tile / C col-within-group
  const int g4 = lane >> 4;    // k-slice group
  const int seg = lane & 7;    // 16B segment within a 128B x-row
  const int ktl = lane >> 3;   // which neighbor this lane fetches
  const int swz = (r & 7) << 4;
  const int rdbase = (r << 10) + (g4 << 5);

  float sacc[4] = {0.f, 0.f, 0.f, 0.f};
  float qacc[4] = {0.f, 0.f, 0.f, 0.f};

  for (int k = 0; k < cnt; ++k) {
    const int t = start + k;
    const int n0 = t << 4;

    // Direct idx loads: addresses land in VGPRs before the gather burst.
    int idxv[16];
    #pragma unroll
    for (int m = 0; m < 16; ++m)
      idxv[m] = neigh[(n0 + m) * 8 + ktl];

    // WAR guard: previous tile's ds_reads fully retired before overwriting.
    asm volatile("s_waitcnt lgkmcnt(0)" ::: "memory");
    __builtin_amdgcn_sched_barrier(0);

    // 16 gathers back-to-back: instr j stages output-row j's 8 neighbor rows.
    // Source segment pre-permuted (seg^(j&7)) = XOR-swizzled linear LDS
    // layout (Rule 21); read side applies the same involution.
    #pragma unroll
    for (int j = 0; j < 16; ++j) {
      const float* src = x + (size_t)idxv[j] * 32 + ((seg ^ (j & 7)) << 2);
      GLOAD_LDS16(src, Abuf + j * 1024);
    }

    // Drain gathers (count-independent -> immune to scheduler reordering).
    asm volatile("s_waitcnt vmcnt(0)" ::: "memory");
    __builtin_amdgcn_sched_barrier(0);

    f32x4 acc[4];
    #pragma unroll
    for (int ct = 0; ct < 4; ++ct) acc[ct] = (f32x4){0.f, 0.f, 0.f, 0.f};

    #pragma unroll
    for (int kt = 0; kt < 8; ++kt) {
      const int o0 = rdbase + (kt << 7);
      const f32x4 a0 = *reinterpret_cast<const f32x4*>(Abuf + (o0 ^ swz));
      const f32x4 a1 = *reinterpret_cast<const f32x4*>(Abuf + ((o0 + 16) ^ swz));
      union { bf16x8 v; __hip_bfloat162 h[4]; } af;
      af.h[0] = __float22bfloat162_rn(make_float2(a0[0], a0[1]));
      af.h[1] = __float22bfloat162_rn(make_float2(a0[2], a0[3]));
      af.h[2] = __float22bfloat162_rn(make_float2(a1[0], a1[1]));
      af.h[3] = __float22bfloat162_rn(make_float2(a1[2], a1[3]));
      #pragma unroll
      for (int ct = 0; ct < 4; ++ct)
        acc[ct] = __builtin_amdgcn_mfma_f32_16x16x32_bf16(af.v, bf[kt][ct],
                                                          acc[ct], 0, 0, 0);
    }

    // C write: col = ct*16 + r, row = g4*4 + j; BN partials from unrounded f32.
    const int rbase = n0 + g4 * 4;
    #pragma unroll
    for (int ct = 0; ct < 4; ++ct) {
      #pragma unroll
      for (int j = 0; j < 4; ++j) {
        const int off = (rbase + j) * 64 + ct * 16 + r;
        if (BF16OUT) outb[off] = f2bf(acc[ct][j]);
        else         outf[off] = acc[ct][j];
      }
      sacc[ct] += acc[ct][0] + acc[ct][1] + acc[ct][2] + acc[ct][3];
      qacc[ct] += acc[ct][0] * acc[ct][0] + acc[ct][1] * acc[ct][1] +
                  acc[ct][2] * acc[ct][2] + acc[ct][3] * acc[ct][3];
    }
  }

  // Block-level BN stats reduction: shuffle across g4 groups, LDS combine
  // across waves, 128 atomics per block.
  #pragma unroll
  for (int ct = 0; ct < 4; ++ct) {
    sacc[ct] += __shfl_xor(sacc[ct], 16);
    qacc[ct] += __shfl_xor(qacc[ct], 16);
    sacc[ct] += __shfl_xor(sacc[ct], 32);
    qacc[ct] += __shfl_xor(qacc[ct], 32);
  }
  if (lane < 16) {
    #pragma unroll
    for (int ct = 0; ct < 4; ++ct) {
      wpart[widx][ct * 16 + lane] = sacc[ct];
      wpart[widx][64 + ct * 16 + lane] = qacc[ct];
    }
  }
  __syncthreads();
  if (tid < 128) {
    atomicAdd(&stats[tid], wpart[0][tid] + wpart[1][tid] +
                           wpart[2][tid] + wpart[3][tid]);
  }
}

// Finalize BN: y = (v - mean) * rsqrt(var+eps) * gamma + beta.
// BF16IN: read bf16 intermediate (L3-hot), write f32 output.
template <bool BF16IN>
__global__ __launch_bounds__(256)
void k_bn(float* __restrict__ out, const unsigned short* __restrict__ inb,
          const float* __restrict__ stats, const float* __restrict__ gamma,
          const float* __restrict__ beta) {
  __shared__ float sc[64], bs[64];
  if (threadIdx.x < 64) {
    const int d = threadIdx.x;
    const float inv = 1.0f / (float)N_OUT_ROWS;
    const float mean = stats[d] * inv;
    const float var = stats[64 + d] * inv - mean * mean;
    const float rstd = rsqrtf(var + BN_EPS);
    const float scale = rstd * gamma[d];
    sc[d] = scale;
    bs[d] = beta[d] - mean * scale;
  }
  __syncthreads();

  if (BF16IN) {
    const int total8 = N_OUT_ROWS * 64 / 8;  // 2M chunks of 8 elems
    for (int i = blockIdx.x * blockDim.x + threadIdx.x; i < total8;
         i += gridDim.x * blockDim.x) {
      const int d0 = (i & 7) << 3;  // 8 chunks per 64-ch row
      const u16x8 v = *reinterpret_cast<const u16x8*>(inb + i * 8);
      float4 o0, o1;
      o0.x = bf2f(v[0]) * sc[d0 + 0] + bs[d0 + 0];
      o0.y = bf2f(v[1]) * sc[d0 + 1] + bs[d0 + 1];
      o0.z = bf2f(v[2]) * sc[d0 + 2] + bs[d0 + 2];
      o0.w = bf2f(v[3]) * sc[d0 + 3] + bs[d0 + 3];
      o1.x = bf2f(v[4]) * sc[d0 + 4] + bs[d0 + 4];
      o1.y = bf2f(v[5]) * sc[d0 + 5] + bs[d0 + 5];
      o1.z = bf2f(v[6]) * sc[d0 + 6] + bs[d0 + 6];
      o1.w = bf2f(v[7]) * sc[d0 + 7] + bs[d0 + 7];
      reinterpret_cast<float4*>(out)[i * 2] = o0;
      reinterpret_cast<float4*>(out)[i * 2 + 1] = o1;
    }
  } else {
    const int total4 = N_OUT_ROWS * 64 / 4;
    float4* o4 = reinterpret_cast<float4*>(out);
    for (int i = blockIdx.x * blockDim.x + threadIdx.x; i < total4;
         i += gridDim.x * blockDim.x) {
      const int d0 = (i & 15) << 2;
      float4 v = o4[i];
      v.x = v.x * sc[d0]     + bs[d0];
      v.y = v.y * sc[d0 + 1] + bs[d0 + 1];
      v.z = v.z * sc[d0 + 2] + bs[d0 + 2];
      v.w = v.w * sc[d0 + 3] + bs[d0 + 3];
      o4[i] = v;
    }
  }
}

extern "C" void kernel_launch(void* const* d_in, const int* in_sizes, int n_in,
                              void* d_out, int out_size, void* d_ws, size_t ws_size,
                              hipStream_t stream) {
  const float* x     = (const float*)d_in[0];
  const int*   neigh = (const int*)d_in[1];
  const float* w     = (const float*)d_in[2];
  const float* gamma = (const float*)d_in[3];
  const float* beta  = (const float*)d_in[4];
  float* out = (float*)d_out;

  float* stats = (float*)d_ws;                                    // 512 B
  unsigned short* bfrag = (unsigned short*)((char*)d_ws + 1024);  // 32 KB
  unsigned short* obf = (unsigned short*)((char*)d_ws + 65536);   // 32 MB

  const bool bf16path =
      ws_size >= (size_t)65536 + (size_t)N_OUT_ROWS * 64 * 2;

  k_prep<<<8, 256, 0, stream>>>(w, bfrag, stats);
  if (bf16path) {
    k_gemm<true><<<NBLK, 256, 0, stream>>>(x, neigh, bfrag, nullptr, obf, stats);
    k_bn<true><<<2048, 256, 0, stream>>>(out, obf, stats, gamma, beta);
  } else {
    k_gemm<false><<<NBLK, 256, 0, stream>>>(x, neigh, bfrag, out, nullptr, stats);
    k_bn<false><<<2048, 256, 0, stream>>>(out, nullptr, stats, gamma, beta);
  }
}